// Round 5
// baseline (17772.583 us; speedup 1.0000x reference)
//
#include <hip/hip_runtime.h>
#include <stdint.h>

#define B_    4
#define Q_    1024
#define H_    32
#define HKV_  8
#define D_    128
#define HID_  4096
#define NQKV_ 6144
#define SCALE_ 0.08838834764831845f

// ---------------- naive f32 GEMM ----------------
// C[row0+m][col0+n] (ldC) = sum_k A[row0+m][k] * B[k][colOff+col0+n]  (B row-major, ldB)
__global__ __launch_bounds__(256) void k_gemm_f32(const float* __restrict__ A,
                                                  const float* __restrict__ B,
                                                  float* __restrict__ C,
                                                  int K, int ldB, int colOff, int ldC) {
  __shared__ float As[64][17];   // [m][kk]
  __shared__ float Bs[16][68];   // [kk][n]
  const int tid = threadIdx.x;
  const int tx = tid & 15, ty = tid >> 4;
  const size_t row0 = (size_t)blockIdx.y * 64;
  const size_t col0 = (size_t)blockIdx.x * 64;
  const int ar = tid >> 2, ak = (tid & 3) * 4;   // A-stage: 4 threads per row
  const int bk = tid >> 4, bn = (tid & 15) * 4;  // B-stage: 16 threads per k-row
  float acc[4][4] = {};
  for (int k0 = 0; k0 < K; k0 += 16) {
    __syncthreads();
    {
      float4 av = *reinterpret_cast<const float4*>(A + (row0 + ar) * K + k0 + ak);
      As[ar][ak] = av.x; As[ar][ak + 1] = av.y; As[ar][ak + 2] = av.z; As[ar][ak + 3] = av.w;
      float4 bv = *reinterpret_cast<const float4*>(B + (size_t)(k0 + bk) * ldB + colOff + col0 + bn);
      Bs[bk][bn] = bv.x; Bs[bk][bn + 1] = bv.y; Bs[bk][bn + 2] = bv.z; Bs[bk][bn + 3] = bv.w;
    }
    __syncthreads();
#pragma unroll
    for (int kk = 0; kk < 16; ++kk) {
      float av[4], bv[4];
#pragma unroll
      for (int i = 0; i < 4; ++i) av[i] = As[ty * 4 + i][kk];
#pragma unroll
      for (int j = 0; j < 4; ++j) bv[j] = Bs[kk][tx * 4 + j];
#pragma unroll
      for (int i = 0; i < 4; ++i)
#pragma unroll
        for (int j = 0; j < 4; ++j)
          acc[i][j] += av[i] * bv[j];
    }
  }
#pragma unroll
  for (int i = 0; i < 4; ++i)
#pragma unroll
    for (int j = 0; j < 4; ++j)
      C[(row0 + ty * 4 + i) * (size_t)ldC + col0 + tx * 4 + j] = acc[i][j];
}

// ---------------- NeoX RoPE, in place; position derived: pos = t mod 1024 ----------------
__global__ __launch_bounds__(256) void k_rope_inplace(float* __restrict__ x, int nh) {
  const int t = blockIdx.x;
  const float pos = (float)(t & (Q_ - 1));
  float* row = x + (size_t)t * nh * D_;
  for (int i = threadIdx.x; i < nh * 64; i += 256) {
    int h = i >> 6, j = i & 63;
    float fr = powf(10000.0f, -(float)j * (1.0f / 64.0f));
    float sn, cs;
    sincosf(pos * fr, &sn, &cs);
    float x1 = row[h * D_ + j];
    float x2 = row[h * D_ + 64 + j];
    row[h * D_ + j]      = x1 * cs - x2 * sn;
    row[h * D_ + 64 + j] = x1 * sn + x2 * cs;
  }
}

// ---------------- f32 flash attention; q rows in d_out overwritten in place -------------
// slot for (b,s) = b*1024+s (derived identity paging); k/v layout [slot][HKV][D]
__global__ __launch_bounds__(256) void k_attn_f32(float* __restrict__ qa,
                                                  const float* __restrict__ kws,
                                                  const float* __restrict__ vws) {
  const int qt = blockIdx.x, h = blockIdx.y, b = blockIdx.z;
  const int hkv = h >> 2;
  const int tid = threadIdx.x, wave = tid >> 6, lane = tid & 63;
  const float NEG_INF = -__builtin_inff();
  for (int ri = 0; ri < 16; ++ri) {
    const int qr = qt * 64 + wave * 16 + ri;
    float* qp = qa + (size_t)(b * Q_ + qr) * HID_ + h * D_;
    const float q1 = qp[lane];
    const float q2 = qp[lane + 64];
    float m = NEG_INF, l = 0.f, a1 = 0.f, a2 = 0.f;
    for (int s = 0; s <= qr; ++s) {
      const float* kp = kws + (size_t)(b * Q_ + s) * (HKV_ * D_) + hkv * D_;
      float sc = q1 * kp[lane] + q2 * kp[lane + 64];
      sc += __shfl_xor(sc, 1);
      sc += __shfl_xor(sc, 2);
      sc += __shfl_xor(sc, 4);
      sc += __shfl_xor(sc, 8);
      sc += __shfl_xor(sc, 16);
      sc += __shfl_xor(sc, 32);
      sc *= SCALE_;
      float mn = fmaxf(m, sc);
      float f = expf(m - mn);     // m=-inf first iter -> 0
      float p = expf(sc - mn);
      const float* vp = vws + (size_t)(b * Q_ + s) * (HKV_ * D_) + hkv * D_;
      l = l * f + p;
      a1 = a1 * f + p * vp[lane];
      a2 = a2 * f + p * vp[lane + 64];
      m = mn;
    }
    const float inv = 1.0f / l;
    qp[lane]      = a1 * inv;
    qp[lane + 64] = a2 * inv;
  }
}

// ---------------- f32 copy ----------------
__global__ __launch_bounds__(256) void k_copy(const float* __restrict__ src,
                                              float* __restrict__ dst, int n) {
  int i = (blockIdx.x * 256 + threadIdx.x) * 4;
  if (i + 3 < n) *reinterpret_cast<float4*>(dst + i) = *reinterpret_cast<const float4*>(src + i);
}

// ---------------- launch ----------------
extern "C" void kernel_launch(void* const* d_in, const int* in_sizes, int n_in,
                              void* d_out, int out_size, void* d_ws, size_t ws_size,
                              hipStream_t stream) {
  const float* hidden = (const float*)d_in[0];
  const float* w_qkv  = (const float*)d_in[1];
  const float* w_o    = (const float*)d_in[2];
  float* out = (float*)d_out;
  float* wsf = (float*)d_ws;
  // workspace (peak 67.1 MB):
  float* k_ws = wsf;                       // [4096][1024] f32  (16.8 MB)
  float* v_ws = wsf + 4096 * 1024;         // [4096][1024] f32  (16.8 MB)
  float* attn = wsf;                       // [4096][4096] f32  (67.1 MB, after k/v dead)

  // q = hidden @ w_qkv[:, 0:4096]  -> d_out
  k_gemm_f32<<<dim3(64, 64), dim3(256), 0, stream>>>(hidden, w_qkv, out, HID_, NQKV_, 0, HID_);
  // k = hidden @ w_qkv[:, 4096:5120] -> k_ws
  k_gemm_f32<<<dim3(16, 64), dim3(256), 0, stream>>>(hidden, w_qkv, k_ws, HID_, NQKV_, 4096, 1024);
  // v = hidden @ w_qkv[:, 5120:6144] -> v_ws
  k_gemm_f32<<<dim3(16, 64), dim3(256), 0, stream>>>(hidden, w_qkv, v_ws, HID_, NQKV_, 5120, 1024);
  // rope q (32 heads, in d_out) and k (8 heads, in k_ws); pos = t mod 1024
  k_rope_inplace<<<dim3(B_ * Q_), dim3(256), 0, stream>>>(out, H_);
  k_rope_inplace<<<dim3(B_ * Q_), dim3(256), 0, stream>>>(k_ws, HKV_);
  // attention in place on d_out
  k_attn_f32<<<dim3(16, 32, 4), dim3(256), 0, stream>>>(out, k_ws, v_ws);
  // move attn to ws, then out = attn @ w_o
  k_copy<<<dim3(16384), dim3(256), 0, stream>>>(out, attn, B_ * Q_ * HID_);
  k_gemm_f32<<<dim3(64, 64), dim3(256), 0, stream>>>(attn, w_o, out, HID_, HID_, 0, HID_);
}

// Round 6
// 753.147 us; speedup vs baseline: 23.5978x; 23.5978x over previous
//
#include <hip/hip_runtime.h>
#include <stdint.h>

typedef short short8  __attribute__((ext_vector_type(8)));
typedef short short4v __attribute__((ext_vector_type(4)));
typedef float f32x4   __attribute__((ext_vector_type(4)));

#define B_    4
#define Q_    1024
#define H_    32
#define HKV_  8
#define D_    128
#define HID_  4096
#define NQKV_ 6144
#define SCALE_ 0.08838834764831845f

__device__ __forceinline__ short f2bf(float f) {
  unsigned u = __builtin_bit_cast(unsigned, f);
  u += 0x7fffu + ((u >> 16) & 1u);          // RNE
  return (short)(u >> 16);
}
__device__ __forceinline__ float bf2f(short s) {
  unsigned u = ((unsigned)(unsigned short)s) << 16;
  return __builtin_bit_cast(float, u);
}

__device__ __forceinline__ void gload_lds16(const void* g, void* l) {
  __builtin_amdgcn_global_load_lds(
      (__attribute__((address_space(1))) void*)(uintptr_t)(g),
      (__attribute__((address_space(3))) void*)(l), 16, 0, 0);
}

__device__ __forceinline__ f32x4 mfma16x16x32(short8 a, short8 b, f32x4 c) {
  return __builtin_amdgcn_mfma_f32_16x16x32_bf16(a, b, c, 0, 0, 0);
}

// ---------------- f32 -> bf16 flat convert ----------------
__global__ __launch_bounds__(256) void k_cvt(const float* __restrict__ src,
                                             short* __restrict__ dst, int n) {
  int i = (blockIdx.x * 256 + threadIdx.x) * 4;
  if (i + 3 < n) {
    float4 v = *reinterpret_cast<const float4*>(src + i);
    short4v o;
    o[0] = f2bf(v.x); o[1] = f2bf(v.y); o[2] = f2bf(v.z); o[3] = f2bf(v.w);
    *reinterpret_cast<short4v*>(dst + i) = o;
  }
}

// ------- f32 [R][C] cols [cb, cb+32*gridDim.x) -> bf16 [cw][R] transpose-convert -------
__global__ __launch_bounds__(256) void k_cvt_t(const float* __restrict__ src,
                                               short* __restrict__ dst, int R, int C, int cb) {
  __shared__ float tile[32][33];
  int c0 = cb + blockIdx.x * 32, r0 = blockIdx.y * 32;
  int tx = threadIdx.x & 31, ty = threadIdx.x >> 5;
#pragma unroll
  for (int i = 0; i < 4; ++i)
    tile[ty + i * 8][tx] = src[(size_t)(r0 + ty + i * 8) * C + c0 + tx];
  __syncthreads();
#pragma unroll
  for (int i = 0; i < 4; ++i)
    dst[(size_t)(c0 - cb + ty + i * 8) * R + r0 + tx] = f2bf(tile[tx][ty + i * 8]);
}

// ------- MFMA GEMM (m97 structure): C[M][ldC] cols += colBase; A[M][K], Bt[Nt][K] -------
__device__ __forceinline__ void storeC(short* C, size_t idx, float v) { C[idx] = f2bf(v); }
__device__ __forceinline__ void storeC(float* C, size_t idx, float v) { C[idx] = v; }

template <typename OT>
__global__ __launch_bounds__(256) void k_gemm_bt(const short* __restrict__ A,
                                                 const short* __restrict__ Bt,
                                                 OT* __restrict__ C, int K, int ldC, int colBase) {
  __shared__ alignas(16) short Asm[128 * 32];
  __shared__ alignas(16) short Bsm[128 * 32];
  const int tid = threadIdx.x;
  const int wave = tid >> 6, lane = tid & 63;
  const int G = lane >> 4, r = lane & 15;
  const int wm = wave >> 1, wn = wave & 1;
  const size_t Arow0 = (size_t)blockIdx.y * 128;
  const size_t Brow0 = (size_t)blockIdx.x * 128;
  const int ldrow = lane >> 2, ldcol = (lane & 3) * 8;
  f32x4 acc[4][4] = {};
  for (int k0 = 0; k0 < K; k0 += 32) {
    __syncthreads();
#pragma unroll
    for (int i = 0; i < 2; ++i) {
      int c = wave * 2 + i;
      gload_lds16(A + (Arow0 + c * 16 + ldrow) * K + k0 + ldcol, &Asm[c * 512]);
      gload_lds16(Bt + (Brow0 + c * 16 + ldrow) * K + k0 + ldcol, &Bsm[c * 512]);
    }
    asm volatile("s_waitcnt vmcnt(0)" ::: "memory");
    __syncthreads();
    short8 af[4], bf[4];
#pragma unroll
    for (int i = 0; i < 4; ++i)
      af[i] = *reinterpret_cast<const short8*>(&Asm[(wm * 64 + i * 16 + r) * 32 + G * 8]);
#pragma unroll
    for (int j = 0; j < 4; ++j)
      bf[j] = *reinterpret_cast<const short8*>(&Bsm[(wn * 64 + j * 16 + r) * 32 + G * 8]);
#pragma unroll
    for (int i = 0; i < 4; ++i)
#pragma unroll
      for (int j = 0; j < 4; ++j)
        acc[i][j] = mfma16x16x32(af[i], bf[j], acc[i][j]);
  }
#pragma unroll
  for (int i = 0; i < 4; ++i)
#pragma unroll
    for (int j = 0; j < 4; ++j)
#pragma unroll
      for (int rr = 0; rr < 4; ++rr) {
        size_t row = Arow0 + wm * 64 + i * 16 + G * 4 + rr;
        size_t col = (size_t)colBase + Brow0 + wn * 64 + j * 16 + r;
        storeC(C, row * (size_t)ldC + col, acc[i][j][rr]);
      }
}

// ---------------- NeoX RoPE in place on bf16 rows; pos = t & 1023 (derived) ----------------
__global__ __launch_bounds__(256) void k_rope_bf(short* __restrict__ x, int nh, int ld) {
  const int t = blockIdx.x;
  const float pos = (float)(t & (Q_ - 1));
  short* row = x + (size_t)t * ld;
  for (int i = threadIdx.x; i < nh * 64; i += 256) {
    int h = i >> 6, j = i & 63;
    float fr = powf(10000.0f, -(float)j * (1.0f / 64.0f));
    float sn, cs;
    sincosf(pos * fr, &sn, &cs);
    float x1 = bf2f(row[h * D_ + j]);
    float x2 = bf2f(row[h * D_ + 64 + j]);
    row[h * D_ + j]      = f2bf(x1 * cs - x2 * sn);
    row[h * D_ + 64 + j] = f2bf(x1 * sn + x2 * cs);
  }
}

// ---------------- MFMA flash attention (causal, GQA rep=4) ----------------
// q bf16 [B*Q][HID] (strided rows in d_out); kv bf16 [B*Q][2048] (k cols 0..1023, v 1024..2047)
__global__ __launch_bounds__(256) void k_attn(const short* __restrict__ qbf,
                                              const short* __restrict__ kv,
                                              short* __restrict__ attn) {
  const int qt = blockIdx.x;   // 16
  const int h  = blockIdx.y;   // 32
  const int b  = blockIdx.z;   // 4
  const int hkv = h >> 2;
  const int tid = threadIdx.x, wave = tid >> 6, lane = tid & 63;
  const int G = lane >> 4, r = lane & 15;
  const int q0w = qt * 64 + wave * 16;
  const float NEG_INF = -__builtin_inff();
  __shared__ alignas(16) short Ksm[32 * 136];   // [s][d] padded
  __shared__ alignas(16) short Vsm[128 * 40];   // V^T [d][s] padded, 16B-aligned frags
  __shared__ alignas(16) short Psm[4][16][40];  // per-wave P [q][s]
  short8 qf[4];
  {
    const short* qrow = qbf + ((size_t)(b * Q_ + q0w + r)) * HID_ + h * D_;
#pragma unroll
    for (int ds = 0; ds < 4; ++ds)
      qf[ds] = *reinterpret_cast<const short8*>(qrow + ds * 32 + G * 8);
  }
  f32x4 acc[8] = {};
  float m_run = NEG_INF, l_run = 0.f;
  const int ntiles = qt * 2 + 2;
  const int my_q = q0w + r;
  const int my_q_hi = q0w + 15;
  const int krow = tid >> 3, kd0 = (tid & 7) * 16;
  const int vs = tid & 31, vdg = tid >> 5;
  for (int st = 0; st < ntiles; ++st) {
    __syncthreads();
    {
      const short* gk = kv + ((size_t)(b * Q_ + st * 32 + krow)) * 2048 + hkv * D_ + kd0;
      *reinterpret_cast<uint4*>(&Ksm[krow * 136 + kd0])     = *reinterpret_cast<const uint4*>(gk);
      *reinterpret_cast<uint4*>(&Ksm[krow * 136 + kd0 + 8]) = *reinterpret_cast<const uint4*>(gk + 8);
      const short* gv = kv + ((size_t)(b * Q_ + st * 32 + vs)) * 2048 + 1024 + hkv * D_ + vdg * 16;
      short tmp[16];
      *reinterpret_cast<uint4*>(&tmp[0]) = *reinterpret_cast<const uint4*>(gv);
      *reinterpret_cast<uint4*>(&tmp[8]) = *reinterpret_cast<const uint4*>(gv + 8);
#pragma unroll
      for (int i = 0; i < 16; ++i) Vsm[(vdg * 16 + i) * 40 + vs] = tmp[i];
    }
    __syncthreads();
    if (st * 32 <= my_q_hi) {
      // S^T = K*Q^T: lane holds q=r, s = st*32 + sb*16 + G*4 + reg
      f32x4 sacc[2] = {};
#pragma unroll
      for (int sb = 0; sb < 2; ++sb)
#pragma unroll
        for (int ds = 0; ds < 4; ++ds) {
          short8 kf = *reinterpret_cast<const short8*>(&Ksm[(sb * 16 + r) * 136 + ds * 32 + G * 8]);
          sacc[sb] = mfma16x16x32(kf, qf[ds], sacc[sb]);
        }
      float vals[8];
      float mymax = NEG_INF;
#pragma unroll
      for (int sb = 0; sb < 2; ++sb)
#pragma unroll
        for (int j = 0; j < 4; ++j) {
          int sIdx = st * 32 + sb * 16 + G * 4 + j;
          float v = sacc[sb][j] * SCALE_;
          v = (sIdx <= my_q) ? v : NEG_INF;
          vals[sb * 4 + j] = v;
          mymax = fmaxf(mymax, v);
        }
      mymax = fmaxf(mymax, __shfl_xor(mymax, 16));
      mymax = fmaxf(mymax, __shfl_xor(mymax, 32));
      float m_new = fmaxf(m_run, mymax);
      float factor = __expf(m_run - m_new);
      float psum = 0.f;
      float pv_[8];
#pragma unroll
      for (int i = 0; i < 8; ++i) {
        float p = __expf(vals[i] - m_new);
        psum += p;
        pv_[i] = p;
      }
      psum += __shfl_xor(psum, 16);
      psum += __shfl_xor(psum, 32);
      l_run = l_run * factor + psum;
      m_run = m_new;
      // P -> per-wave LDS, canonical GEMM-A layout
#pragma unroll
      for (int i = 0; i < 8; ++i)
        Psm[wave][r][(i >> 2) * 16 + G * 4 + (i & 3)] = f2bf(pv_[i]);
      asm volatile("s_waitcnt lgkmcnt(0)" ::: "memory");
      __builtin_amdgcn_sched_barrier(0);
      short8 pf = *reinterpret_cast<const short8*>(&Psm[wave][r][G * 8]);
      float frow[4];
#pragma unroll
      for (int rr = 0; rr < 4; ++rr) frow[rr] = __shfl(factor, G * 4 + rr);
#pragma unroll
      for (int dt = 0; dt < 8; ++dt)
#pragma unroll
        for (int rr = 0; rr < 4; ++rr) acc[dt][rr] *= frow[rr];
#pragma unroll
      for (int dt = 0; dt < 8; ++dt) {
        short8 vf = *reinterpret_cast<const short8*>(&Vsm[(dt * 16 + r) * 40 + G * 8]);
        acc[dt] = mfma16x16x32(pf, vf, acc[dt]);
      }
    }
  }
  float inv = 1.0f / l_run;
  float irow[4];
#pragma unroll
  for (int rr = 0; rr < 4; ++rr) irow[rr] = __shfl(inv, G * 4 + rr);
#pragma unroll
  for (int dt = 0; dt < 8; ++dt)
#pragma unroll
    for (int rr = 0; rr < 4; ++rr) {
      size_t rowi = (size_t)(b * Q_ + q0w + G * 4 + rr) * HID_;
      attn[rowi + h * D_ + dt * 16 + r] = f2bf(acc[dt][rr] * irow[rr]);
    }
}

// ---------------- launch ----------------
extern "C" void kernel_launch(void* const* d_in, const int* in_sizes, int n_in,
                              void* d_out, int out_size, void* d_ws, size_t ws_size,
                              hipStream_t stream) {
  const float* hidden = (const float*)d_in[0];
  const float* w_qkv  = (const float*)d_in[1];
  const float* w_o    = (const float*)d_in[2];
  float* out = (float*)d_out;
  char* ws = (char*)d_ws;
  // ws layout (peak 64 MiB == round-5-proven capacity):
  short* hid_bf  = (short*)(ws + 0);                 // 32 MiB, dead after GEMM1
  short* stage   = (short*)(ws + 33554432);          // 16 MiB, wqkvT thirds
  short* kv_ws   = (short*)(ws + 50331648);          // 16 MiB, [4096][2048] bf16
  short* attn_bf = hid_bf;                           // 32 MiB, after GEMM1
  short* woT     = stage;                            // 32 MiB (ws+32M..64M), after attention
  short* q_bf    = (short*)d_out;                    // 32 MiB scratch in d_out (dead before GEMM2)

  k_cvt<<<dim3(16384), dim3(256), 0, stream>>>(hidden, hid_bf, HID_ * B_ * Q_);
  // GEMM1 in three 2048-col passes (stage buffer is only 16 MiB)
  for (int p = 0; p < 3; ++p) {
    k_cvt_t<<<dim3(64, 128), dim3(256), 0, stream>>>(w_qkv, stage, HID_, NQKV_, p * 2048);
    if (p < 2)
      k_gemm_bt<short><<<dim3(16, 32), dim3(256), 0, stream>>>(hid_bf, stage, q_bf,
                                                               HID_, HID_, p * 2048);
    else
      k_gemm_bt<short><<<dim3(16, 32), dim3(256), 0, stream>>>(hid_bf, stage, kv_ws,
                                                               HID_, 2048, 0);
  }
  // RoPE in place: q (32 heads, d_out), k (8 heads, kv cols 0..1023)
  k_rope_bf<<<dim3(B_ * Q_), dim3(256), 0, stream>>>(q_bf, H_, HID_);
  k_rope_bf<<<dim3(B_ * Q_), dim3(256), 0, stream>>>(kv_ws, HKV_, 2048);
  // attention -> attn_bf (ws+0)
  k_attn<<<dim3(16, 32, 4), dim3(256), 0, stream>>>(q_bf, kv_ws, attn_bf);
  // w_o transpose (into ws+32M..64M; kv dead now), then GEMM2 -> d_out f32
  k_cvt_t<<<dim3(128, 128), dim3(256), 0, stream>>>(w_o, woT, HID_, HID_, 0);
  k_gemm_bt<float><<<dim3(32, 32), dim3(256), 0, stream>>>(attn_bf, woT, out,
                                                           HID_, HID_, 0);
}

// Round 8
// 704.508 us; speedup vs baseline: 25.2270x; 1.0690x over previous
//
#include <hip/hip_runtime.h>
#include <stdint.h>

typedef short short8  __attribute__((ext_vector_type(8)));
typedef short short4v __attribute__((ext_vector_type(4)));
typedef float f32x4   __attribute__((ext_vector_type(4)));

#define B_    4
#define Q_    1024
#define H_    32
#define HKV_  8
#define D_    128
#define HID_  4096
#define NQKV_ 6144
#define SCALE_ 0.08838834764831845f

__device__ __forceinline__ short f2bf(float f) {
  unsigned u = __builtin_bit_cast(unsigned, f);
  u += 0x7fffu + ((u >> 16) & 1u);          // RNE
  return (short)(u >> 16);
}
__device__ __forceinline__ float bf2f(short s) {
  unsigned u = ((unsigned)(unsigned short)s) << 16;
  return __builtin_bit_cast(float, u);
}

__device__ __forceinline__ void gload_lds16(const void* g, void* l) {
  __builtin_amdgcn_global_load_lds(
      (__attribute__((address_space(1))) void*)(uintptr_t)(g),
      (__attribute__((address_space(3))) void*)(l), 16, 0, 0);
}

__device__ __forceinline__ f32x4 mfma16x16x32(short8 a, short8 b, f32x4 c) {
  return __builtin_amdgcn_mfma_f32_16x16x32_bf16(a, b, c, 0, 0, 0);
}

// ---------------- f32 -> bf16 flat convert ----------------
__global__ __launch_bounds__(256) void k_cvt(const float* __restrict__ src,
                                             short* __restrict__ dst, int n) {
  int i = (blockIdx.x * 256 + threadIdx.x) * 4;
  if (i + 3 < n) {
    float4 v = *reinterpret_cast<const float4*>(src + i);
    short4v o;
    o[0] = f2bf(v.x); o[1] = f2bf(v.y); o[2] = f2bf(v.z); o[3] = f2bf(v.w);
    *reinterpret_cast<short4v*>(dst + i) = o;
  }
}

// ------- f32 [R][C] -> bf16 [C][R] transpose-convert -------
__global__ __launch_bounds__(256) void k_cvt_t(const float* __restrict__ src,
                                               short* __restrict__ dst, int R, int C) {
  __shared__ float tile[32][33];
  int c0 = blockIdx.x * 32, r0 = blockIdx.y * 32;
  int tx = threadIdx.x & 31, ty = threadIdx.x >> 5;
#pragma unroll
  for (int i = 0; i < 4; ++i)
    tile[ty + i * 8][tx] = src[(size_t)(r0 + ty + i * 8) * C + c0 + tx];
  __syncthreads();
#pragma unroll
  for (int i = 0; i < 4; ++i)
    dst[(size_t)(c0 + ty + i * 8) * R + r0 + tx] = f2bf(tile[tx][ty + i * 8]);
}

// ------- GEMM1 (m97 structure, split store): qkv = hid @ wqkvT^T -------
// A[4096][4096], Bt[6144][4096]; cols 0..4095 -> qout[r][4096], cols 4096..6143 -> kvout[r][2048]
__global__ __launch_bounds__(256) void k_gemm1(const short* __restrict__ A,
                                               const short* __restrict__ Bt,
                                               short* __restrict__ qout,
                                               short* __restrict__ kvout) {
  __shared__ alignas(16) short Asm[128 * 32];
  __shared__ alignas(16) short Bsm[128 * 32];
  const int tid = threadIdx.x;
  const int wave = tid >> 6, lane = tid & 63;
  const int G = lane >> 4, r = lane & 15;
  const int wm = wave >> 1, wn = wave & 1;
  const size_t Arow0 = (size_t)blockIdx.y * 128;
  const size_t Brow0 = (size_t)blockIdx.x * 128;
  const int K = HID_;
  const int ldrow = lane >> 2, ldcol = (lane & 3) * 8;
  f32x4 acc[4][4] = {};
  for (int k0 = 0; k0 < K; k0 += 32) {
    __syncthreads();
#pragma unroll
    for (int i = 0; i < 2; ++i) {
      int c = wave * 2 + i;
      gload_lds16(A + (Arow0 + c * 16 + ldrow) * K + k0 + ldcol, &Asm[c * 512]);
      gload_lds16(Bt + (Brow0 + c * 16 + ldrow) * K + k0 + ldcol, &Bsm[c * 512]);
    }
    asm volatile("s_waitcnt vmcnt(0)" ::: "memory");
    __syncthreads();
    short8 af[4], bf[4];
#pragma unroll
    for (int i = 0; i < 4; ++i)
      af[i] = *reinterpret_cast<const short8*>(&Asm[(wm * 64 + i * 16 + r) * 32 + G * 8]);
#pragma unroll
    for (int j = 0; j < 4; ++j)
      bf[j] = *reinterpret_cast<const short8*>(&Bsm[(wn * 64 + j * 16 + r) * 32 + G * 8]);
#pragma unroll
    for (int i = 0; i < 4; ++i)
#pragma unroll
      for (int j = 0; j < 4; ++j)
        acc[i][j] = mfma16x16x32(af[i], bf[j], acc[i][j]);
  }
#pragma unroll
  for (int i = 0; i < 4; ++i)
#pragma unroll
    for (int j = 0; j < 4; ++j)
#pragma unroll
      for (int rr = 0; rr < 4; ++rr) {
        size_t row = Arow0 + wm * 64 + i * 16 + G * 4 + rr;
        size_t col = Brow0 + wn * 64 + j * 16 + r;
        short v = f2bf(acc[i][j][rr]);
        if (col < (size_t)HID_) qout[row * HID_ + col] = v;
        else                    kvout[row * 2048 + (col - HID_)] = v;
      }
}

// ------- GEMM2 (m97 structure): C[M][N] f32 = A[M][K] * Bt[N][K]^T -------
__global__ __launch_bounds__(256) void k_gemm2(const short* __restrict__ A,
                                               const short* __restrict__ Bt,
                                               float* __restrict__ C) {
  __shared__ alignas(16) short Asm[128 * 32];
  __shared__ alignas(16) short Bsm[128 * 32];
  const int tid = threadIdx.x;
  const int wave = tid >> 6, lane = tid & 63;
  const int G = lane >> 4, r = lane & 15;
  const int wm = wave >> 1, wn = wave & 1;
  const size_t Arow0 = (size_t)blockIdx.y * 128;
  const size_t Brow0 = (size_t)blockIdx.x * 128;
  const int K = HID_;
  const int ldrow = lane >> 2, ldcol = (lane & 3) * 8;
  f32x4 acc[4][4] = {};
  for (int k0 = 0; k0 < K; k0 += 32) {
    __syncthreads();
#pragma unroll
    for (int i = 0; i < 2; ++i) {
      int c = wave * 2 + i;
      gload_lds16(A + (Arow0 + c * 16 + ldrow) * K + k0 + ldcol, &Asm[c * 512]);
      gload_lds16(Bt + (Brow0 + c * 16 + ldrow) * K + k0 + ldcol, &Bsm[c * 512]);
    }
    asm volatile("s_waitcnt vmcnt(0)" ::: "memory");
    __syncthreads();
    short8 af[4], bf[4];
#pragma unroll
    for (int i = 0; i < 4; ++i)
      af[i] = *reinterpret_cast<const short8*>(&Asm[(wm * 64 + i * 16 + r) * 32 + G * 8]);
#pragma unroll
    for (int j = 0; j < 4; ++j)
      bf[j] = *reinterpret_cast<const short8*>(&Bsm[(wn * 64 + j * 16 + r) * 32 + G * 8]);
#pragma unroll
    for (int i = 0; i < 4; ++i)
#pragma unroll
      for (int j = 0; j < 4; ++j)
        acc[i][j] = mfma16x16x32(af[i], bf[j], acc[i][j]);
  }
#pragma unroll
  for (int i = 0; i < 4; ++i)
#pragma unroll
    for (int j = 0; j < 4; ++j)
#pragma unroll
      for (int rr = 0; rr < 4; ++rr) {
        size_t row = Arow0 + wm * 64 + i * 16 + G * 4 + rr;
        size_t col = Brow0 + wn * 64 + j * 16 + r;
        C[row * (size_t)HID_ + col] = acc[i][j][rr];
      }
}

// ---------------- NeoX RoPE in place on bf16 rows; pos = t & 1023 (derived) ----------------
__global__ __launch_bounds__(256) void k_rope_bf(short* __restrict__ x, int nh, int ld) {
  const int t = blockIdx.x;
  const float pos = (float)(t & (Q_ - 1));
  short* row = x + (size_t)t * ld;
  for (int i = threadIdx.x; i < nh * 64; i += 256) {
    int h = i >> 6, j = i & 63;
    float fr = powf(10000.0f, -(float)j * (1.0f / 64.0f));
    float sn, cs;
    sincosf(pos * fr, &sn, &cs);
    float x1 = bf2f(row[h * D_ + j]);
    float x2 = bf2f(row[h * D_ + 64 + j]);
    row[h * D_ + j]      = f2bf(x1 * cs - x2 * sn);
    row[h * D_ + 64 + j] = f2bf(x1 * sn + x2 * cs);
  }
}

// ---------------- MFMA flash attention (causal, GQA rep=4) ----------------
// q bf16 [B*Q][HID]; kv bf16 [B*Q][2048] (k cols 0..1023, v 1024..2047)
__global__ __launch_bounds__(256) void k_attn(const short* __restrict__ qbf,
                                              const short* __restrict__ kv,
                                              short* __restrict__ attn) {
  const int qt = blockIdx.x;   // 16
  const int h  = blockIdx.y;   // 32
  const int b  = blockIdx.z;   // 4
  const int hkv = h >> 2;
  const int tid = threadIdx.x, wave = tid >> 6, lane = tid & 63;
  const int G = lane >> 4, r = lane & 15;
  const int q0w = qt * 64 + wave * 16;
  const float NEG_INF = -__builtin_inff();
  __shared__ alignas(16) short Ksm[32 * 136];   // [s][d] padded
  __shared__ alignas(16) short Vsm[128 * 40];   // V^T [d][s] padded
  __shared__ alignas(16) short Psm[4][16][40];  // per-wave P [q][s]
  short8 qf[4];
  {
    const short* qrow = qbf + ((size_t)(b * Q_ + q0w + r)) * HID_ + h * D_;
#pragma unroll
    for (int ds = 0; ds < 4; ++ds)
      qf[ds] = *reinterpret_cast<const short8*>(qrow + ds * 32 + G * 8);
  }
  f32x4 acc[8] = {};
  float m_run = NEG_INF, l_run = 0.f;
  const int ntiles = qt * 2 + 2;
  const int my_q = q0w + r;
  const int my_q_hi = q0w + 15;
  const int krow = tid >> 3, kd0 = (tid & 7) * 16;
  const int vs = tid & 31, vdg = tid >> 5;
  for (int st = 0; st < ntiles; ++st) {
    __syncthreads();
    {
      const short* gk = kv + ((size_t)(b * Q_ + st * 32 + krow)) * 2048 + hkv * D_ + kd0;
      *reinterpret_cast<uint4*>(&Ksm[krow * 136 + kd0])     = *reinterpret_cast<const uint4*>(gk);
      *reinterpret_cast<uint4*>(&Ksm[krow * 136 + kd0 + 8]) = *reinterpret_cast<const uint4*>(gk + 8);
      const short* gv = kv + ((size_t)(b * Q_ + st * 32 + vs)) * 2048 + 1024 + hkv * D_ + vdg * 16;
      short tmp[16];
      *reinterpret_cast<uint4*>(&tmp[0]) = *reinterpret_cast<const uint4*>(gv);
      *reinterpret_cast<uint4*>(&tmp[8]) = *reinterpret_cast<const uint4*>(gv + 8);
#pragma unroll
      for (int i = 0; i < 16; ++i) Vsm[(vdg * 16 + i) * 40 + vs] = tmp[i];
    }
    __syncthreads();
    if (st * 32 <= my_q_hi) {
      f32x4 sacc[2] = {};
#pragma unroll
      for (int sb = 0; sb < 2; ++sb)
#pragma unroll
        for (int ds = 0; ds < 4; ++ds) {
          short8 kf = *reinterpret_cast<const short8*>(&Ksm[(sb * 16 + r) * 136 + ds * 32 + G * 8]);
          sacc[sb] = mfma16x16x32(kf, qf[ds], sacc[sb]);
        }
      float vals[8];
      float mymax = NEG_INF;
#pragma unroll
      for (int sb = 0; sb < 2; ++sb)
#pragma unroll
        for (int j = 0; j < 4; ++j) {
          int sIdx = st * 32 + sb * 16 + G * 4 + j;
          float v = sacc[sb][j] * SCALE_;
          v = (sIdx <= my_q) ? v : NEG_INF;
          vals[sb * 4 + j] = v;
          mymax = fmaxf(mymax, v);
        }
      mymax = fmaxf(mymax, __shfl_xor(mymax, 16));
      mymax = fmaxf(mymax, __shfl_xor(mymax, 32));
      float m_new = fmaxf(m_run, mymax);
      float factor = __expf(m_run - m_new);
      float psum = 0.f;
      float pv_[8];
#pragma unroll
      for (int i = 0; i < 8; ++i) {
        float p = __expf(vals[i] - m_new);
        psum += p;
        pv_[i] = p;
      }
      psum += __shfl_xor(psum, 16);
      psum += __shfl_xor(psum, 32);
      l_run = l_run * factor + psum;
      m_run = m_new;
#pragma unroll
      for (int i = 0; i < 8; ++i)
        Psm[wave][r][(i >> 2) * 16 + G * 4 + (i & 3)] = f2bf(pv_[i]);
      asm volatile("s_waitcnt lgkmcnt(0)" ::: "memory");
      __builtin_amdgcn_sched_barrier(0);
      short8 pf = *reinterpret_cast<const short8*>(&Psm[wave][r][G * 8]);
      float frow[4];
#pragma unroll
      for (int rr = 0; rr < 4; ++rr) frow[rr] = __shfl(factor, G * 4 + rr);
#pragma unroll
      for (int dt = 0; dt < 8; ++dt)
#pragma unroll
        for (int rr = 0; rr < 4; ++rr) acc[dt][rr] *= frow[rr];
#pragma unroll
      for (int dt = 0; dt < 8; ++dt) {
        short8 vf = *reinterpret_cast<const short8*>(&Vsm[(dt * 16 + r) * 40 + G * 8]);
        acc[dt] = mfma16x16x32(pf, vf, acc[dt]);
      }
    }
  }
  float inv = 1.0f / l_run;
  float irow[4];
#pragma unroll
  for (int rr = 0; rr < 4; ++rr) irow[rr] = __shfl(inv, G * 4 + rr);
#pragma unroll
  for (int dt = 0; dt < 8; ++dt)
#pragma unroll
    for (int rr = 0; rr < 4; ++rr) {
      size_t rowi = (size_t)(b * Q_ + q0w + G * 4 + rr) * HID_;
      attn[rowi + h * D_ + dt * 16 + r] = f2bf(acc[dt][rr] * irow[rr]);
    }
}

// ---------------- launch ----------------
extern "C" void kernel_launch(void* const* d_in, const int* in_sizes, int n_in,
                              void* d_out, int out_size, void* d_ws, size_t ws_size,
                              hipStream_t stream) {
  const float* hidden = (const float*)d_in[0];
  const float* w_qkv  = (const float*)d_in[1];
  const float* w_o    = (const float*)d_in[2];
  float* out = (float*)d_out;
  char* ws = (char*)d_ws;
  char* od = (char*)d_out;
  // scratch layout (ws 64 MiB + d_out 64 MiB):
  //   d_out[ 0:32M) hid_bf (bf16 4096x4096)      -> dead after GEMM1
  //   d_out[32M:64M) q_bf  (bf16 4096x4096)      -> roped; dead after attn
  //   ws   [ 0:48M) wqkvT  (bf16 6144x4096)      -> dead after GEMM1
  //   ws   [48M:64M) kv_ws (bf16 4096x2048)      -> roped; dead after attn
  //   ws   [ 0:32M) attn_bf (after GEMM1)
  //   ws   [32M:64M) woT   (bf16 4096x4096, after attn)
  short* hid_bf  = (short*)(od + 0);
  short* q_bf    = (short*)(od + 33554432);
  short* wqkvT   = (short*)(ws + 0);
  short* kv_ws   = (short*)(ws + 50331648);
  short* attn_bf = (short*)(ws + 0);
  short* woT     = (short*)(ws + 33554432);

  k_cvt<<<dim3(16384), dim3(256), 0, stream>>>(hidden, hid_bf, HID_ * B_ * Q_);
  k_cvt_t<<<dim3(192, 128), dim3(256), 0, stream>>>(w_qkv, wqkvT, HID_, NQKV_);
  // GEMM1: one dispatch, N=6144 (48x32 = 1536 wgs, 6/CU)
  k_gemm1<<<dim3(48, 32), dim3(256), 0, stream>>>(hid_bf, wqkvT, q_bf, kv_ws);
  // RoPE in place: q (32 heads), k (8 heads, kv cols 0..1023)
  k_rope_bf<<<dim3(B_ * Q_), dim3(256), 0, stream>>>(q_bf, H_, HID_);
  k_rope_bf<<<dim3(B_ * Q_), dim3(256), 0, stream>>>(kv_ws, HKV_, 2048);
  // attention -> attn_bf (ws+0, wqkvT dead)
  k_attn<<<dim3(16, 32, 4), dim3(256), 0, stream>>>(q_bf, kv_ws, attn_bf);
  // w_o^T into ws[32M:64M) (wqkvT tail + kv dead after attn), then GEMM2 -> d_out f32
  k_cvt_t<<<dim3(128, 128), dim3(256), 0, stream>>>(w_o, woT, HID_, HID_);
  k_gemm2<<<dim3(32, 32), dim3(256), 0, stream>>>(attn_bf, woT, out);
}

// Round 9
// 684.128 us; speedup vs baseline: 25.9784x; 1.0298x over previous
//
#include <hip/hip_runtime.h>
#include <stdint.h>

typedef short short8  __attribute__((ext_vector_type(8)));
typedef short short4v __attribute__((ext_vector_type(4)));
typedef float f32x4   __attribute__((ext_vector_type(4)));

#define B_    4
#define Q_    1024
#define H_    32
#define HKV_  8
#define D_    128
#define HID_  4096
#define NQKV_ 6144
#define SCALE_ 0.08838834764831845f

__device__ __forceinline__ short f2bf(float f) {
  unsigned u = __builtin_bit_cast(unsigned, f);
  u += 0x7fffu + ((u >> 16) & 1u);          // RNE
  return (short)(u >> 16);
}
__device__ __forceinline__ float bf2f(short s) {
  unsigned u = ((unsigned)(unsigned short)s) << 16;
  return __builtin_bit_cast(float, u);
}

__device__ __forceinline__ void gload_lds16(const void* g, void* l) {
  __builtin_amdgcn_global_load_lds(
      (__attribute__((address_space(1))) void*)(uintptr_t)(g),
      (__attribute__((address_space(3))) void*)(l), 16, 0, 0);
}

__device__ __forceinline__ f32x4 mfma16x16x32(short8 a, short8 b, f32x4 c) {
  return __builtin_amdgcn_mfma_f32_16x16x32_bf16(a, b, c, 0, 0, 0);
}

// ---------------- f32 -> bf16 flat convert ----------------
__global__ __launch_bounds__(256) void k_cvt(const float* __restrict__ src,
                                             short* __restrict__ dst, int n) {
  int i = (blockIdx.x * 256 + threadIdx.x) * 4;
  if (i + 3 < n) {
    float4 v = *reinterpret_cast<const float4*>(src + i);
    short4v o;
    o[0] = f2bf(v.x); o[1] = f2bf(v.y); o[2] = f2bf(v.z); o[3] = f2bf(v.w);
    *reinterpret_cast<short4v*>(dst + i) = o;
  }
}

// ------- f32 [R][C] -> bf16 [C][R] transpose-convert -------
__global__ __launch_bounds__(256) void k_cvt_t(const float* __restrict__ src,
                                               short* __restrict__ dst, int R, int C) {
  __shared__ float tile[32][33];
  int c0 = blockIdx.x * 32, r0 = blockIdx.y * 32;
  int tx = threadIdx.x & 31, ty = threadIdx.x >> 5;
#pragma unroll
  for (int i = 0; i < 4; ++i)
    tile[ty + i * 8][tx] = src[(size_t)(r0 + ty + i * 8) * C + c0 + tx];
  __syncthreads();
#pragma unroll
  for (int i = 0; i < 4; ++i)
    dst[(size_t)(c0 + ty + i * 8) * R + r0 + tx] = f2bf(tile[tx][ty + i * 8]);
}

// ------- GEMM1 (m97 structure, block-uniform split store): qkv = hid @ wqkvT^T -------
// A[4096][4096], Bt[6144][4096]; x-tiles <32 -> qout[r][4096], else -> kvout[r][2048]
__global__ __launch_bounds__(256) void k_gemm1(const short* __restrict__ A,
                                               const short* __restrict__ Bt,
                                               short* __restrict__ qout,
                                               short* __restrict__ kvout) {
  __shared__ alignas(16) short Asm[128 * 32];
  __shared__ alignas(16) short Bsm[128 * 32];
  const int tid = threadIdx.x;
  const int wave = tid >> 6, lane = tid & 63;
  const int G = lane >> 4, r = lane & 15;
  const int wm = wave >> 1, wn = wave & 1;
  const size_t Arow0 = (size_t)blockIdx.y * 128;
  const size_t Brow0 = (size_t)blockIdx.x * 128;
  const int K = HID_;
  const int ldrow = lane >> 2, ldcol = (lane & 3) * 8;
  // block-uniform output select (Brow0 is a multiple of 128; 4096 boundary tile-aligned)
  short* Cb; size_t ldc, cb;
  if (Brow0 < (size_t)HID_) { Cb = qout; ldc = HID_; cb = Brow0; }
  else                      { Cb = kvout; ldc = 2048; cb = Brow0 - HID_; }
  f32x4 acc[4][4] = {};
  for (int k0 = 0; k0 < K; k0 += 32) {
    __syncthreads();
#pragma unroll
    for (int i = 0; i < 2; ++i) {
      int c = wave * 2 + i;
      gload_lds16(A + (Arow0 + c * 16 + ldrow) * K + k0 + ldcol, &Asm[c * 512]);
      gload_lds16(Bt + (Brow0 + c * 16 + ldrow) * K + k0 + ldcol, &Bsm[c * 512]);
    }
    asm volatile("s_waitcnt vmcnt(0)" ::: "memory");
    __syncthreads();
    short8 af[4], bf[4];
#pragma unroll
    for (int i = 0; i < 4; ++i)
      af[i] = *reinterpret_cast<const short8*>(&Asm[(wm * 64 + i * 16 + r) * 32 + G * 8]);
#pragma unroll
    for (int j = 0; j < 4; ++j)
      bf[j] = *reinterpret_cast<const short8*>(&Bsm[(wn * 64 + j * 16 + r) * 32 + G * 8]);
#pragma unroll
    for (int i = 0; i < 4; ++i)
#pragma unroll
      for (int j = 0; j < 4; ++j)
        acc[i][j] = mfma16x16x32(af[i], bf[j], acc[i][j]);
  }
#pragma unroll
  for (int i = 0; i < 4; ++i)
#pragma unroll
    for (int j = 0; j < 4; ++j)
#pragma unroll
      for (int rr = 0; rr < 4; ++rr) {
        size_t row = Arow0 + wm * 64 + i * 16 + G * 4 + rr;
        size_t col = cb + wn * 64 + j * 16 + r;
        Cb[row * ldc + col] = f2bf(acc[i][j][rr]);
      }
}

// ------- GEMM2 (m97 structure): C[M][N] f32 = A[M][K] * Bt[N][K]^T -------
__global__ __launch_bounds__(256) void k_gemm2(const short* __restrict__ A,
                                               const short* __restrict__ Bt,
                                               float* __restrict__ C) {
  __shared__ alignas(16) short Asm[128 * 32];
  __shared__ alignas(16) short Bsm[128 * 32];
  const int tid = threadIdx.x;
  const int wave = tid >> 6, lane = tid & 63;
  const int G = lane >> 4, r = lane & 15;
  const int wm = wave >> 1, wn = wave & 1;
  const size_t Arow0 = (size_t)blockIdx.y * 128;
  const size_t Brow0 = (size_t)blockIdx.x * 128;
  const int K = HID_;
  const int ldrow = lane >> 2, ldcol = (lane & 3) * 8;
  f32x4 acc[4][4] = {};
  for (int k0 = 0; k0 < K; k0 += 32) {
    __syncthreads();
#pragma unroll
    for (int i = 0; i < 2; ++i) {
      int c = wave * 2 + i;
      gload_lds16(A + (Arow0 + c * 16 + ldrow) * K + k0 + ldcol, &Asm[c * 512]);
      gload_lds16(Bt + (Brow0 + c * 16 + ldrow) * K + k0 + ldcol, &Bsm[c * 512]);
    }
    asm volatile("s_waitcnt vmcnt(0)" ::: "memory");
    __syncthreads();
    short8 af[4], bf[4];
#pragma unroll
    for (int i = 0; i < 4; ++i)
      af[i] = *reinterpret_cast<const short8*>(&Asm[(wm * 64 + i * 16 + r) * 32 + G * 8]);
#pragma unroll
    for (int j = 0; j < 4; ++j)
      bf[j] = *reinterpret_cast<const short8*>(&Bsm[(wn * 64 + j * 16 + r) * 32 + G * 8]);
#pragma unroll
    for (int i = 0; i < 4; ++i)
#pragma unroll
      for (int j = 0; j < 4; ++j)
        acc[i][j] = mfma16x16x32(af[i], bf[j], acc[i][j]);
  }
#pragma unroll
  for (int i = 0; i < 4; ++i)
#pragma unroll
    for (int j = 0; j < 4; ++j)
#pragma unroll
      for (int rr = 0; rr < 4; ++rr) {
        size_t row = Arow0 + wm * 64 + i * 16 + G * 4 + rr;
        size_t col = Brow0 + wn * 64 + j * 16 + r;
        C[row * (size_t)HID_ + col] = acc[i][j][rr];
      }
}

// ---------------- NeoX RoPE in place on bf16 rows; pos = t & 1023 (derived) ----------------
__global__ __launch_bounds__(256) void k_rope_bf(short* __restrict__ x, int nh, int ld) {
  const int t = blockIdx.x;
  const float pos = (float)(t & (Q_ - 1));
  short* row = x + (size_t)t * ld;
  for (int i = threadIdx.x; i < nh * 64; i += 256) {
    int h = i >> 6, j = i & 63;
    float fr = powf(10000.0f, -(float)j * (1.0f / 64.0f));
    float sn, cs;
    sincosf(pos * fr, &sn, &cs);
    float x1 = bf2f(row[h * D_ + j]);
    float x2 = bf2f(row[h * D_ + 64 + j]);
    row[h * D_ + j]      = f2bf(x1 * cs - x2 * sn);
    row[h * D_ + 64 + j] = f2bf(x1 * sn + x2 * cs);
  }
}

// ---------------- MFMA flash attention (causal, GQA rep=4) + fused q-RoPE ----------------
// q bf16 [B*Q][HID] (UNroped; roped in-register on load); kv bf16 [B*Q][2048]
__global__ __launch_bounds__(256) void k_attn(const short* __restrict__ qbf,
                                              const short* __restrict__ kv,
                                              short* __restrict__ attn) {
  const int qt = blockIdx.x;   // 16
  const int h  = blockIdx.y;   // 32
  const int b  = blockIdx.z;   // 4
  const int hkv = h >> 2;
  const int tid = threadIdx.x, wave = tid >> 6, lane = tid & 63;
  const int G = lane >> 4, r = lane & 15;
  const int q0w = qt * 64 + wave * 16;
  const float NEG_INF = -__builtin_inff();
  __shared__ alignas(16) short Ksm[32 * 136];   // [s][d] padded
  __shared__ alignas(16) short Vsm[128 * 40];   // V^T [d][s] padded
  __shared__ alignas(16) short Psm[4][16][40];  // per-wave P [q][s]
  short8 qf[4];
  {
    const short* qrow = qbf + ((size_t)(b * Q_ + q0w + r)) * HID_ + h * D_;
#pragma unroll
    for (int ds = 0; ds < 4; ++ds)
      qf[ds] = *reinterpret_cast<const short8*>(qrow + ds * 32 + G * 8);
    // fused NeoX RoPE: lane's frags ds and ds+2 hold the (d, d+64) pair; pos = q row
    const float pos = (float)(q0w + r);
#pragma unroll
    for (int ds2 = 0; ds2 < 2; ++ds2)
#pragma unroll
      for (int u = 0; u < 8; ++u) {
        int d = ds2 * 32 + G * 8 + u;
        float fr = powf(10000.0f, -(float)d * (1.0f / 64.0f));
        float sn, cs;
        sincosf(pos * fr, &sn, &cs);
        float x1 = bf2f(qf[ds2][u]);
        float x2 = bf2f(qf[ds2 + 2][u]);
        qf[ds2][u]     = f2bf(x1 * cs - x2 * sn);
        qf[ds2 + 2][u] = f2bf(x1 * sn + x2 * cs);
      }
  }
  f32x4 acc[8] = {};
  float m_run = NEG_INF, l_run = 0.f;
  const int ntiles = qt * 2 + 2;
  const int my_q = q0w + r;
  const int my_q_hi = q0w + 15;
  const int krow = tid >> 3, kd0 = (tid & 7) * 16;
  const int vs = tid & 31, vdg = tid >> 5;
  for (int st = 0; st < ntiles; ++st) {
    __syncthreads();
    {
      const short* gk = kv + ((size_t)(b * Q_ + st * 32 + krow)) * 2048 + hkv * D_ + kd0;
      *reinterpret_cast<uint4*>(&Ksm[krow * 136 + kd0])     = *reinterpret_cast<const uint4*>(gk);
      *reinterpret_cast<uint4*>(&Ksm[krow * 136 + kd0 + 8]) = *reinterpret_cast<const uint4*>(gk + 8);
      const short* gv = kv + ((size_t)(b * Q_ + st * 32 + vs)) * 2048 + 1024 + hkv * D_ + vdg * 16;
      short tmp[16];
      *reinterpret_cast<uint4*>(&tmp[0]) = *reinterpret_cast<const uint4*>(gv);
      *reinterpret_cast<uint4*>(&tmp[8]) = *reinterpret_cast<const uint4*>(gv + 8);
#pragma unroll
      for (int i = 0; i < 16; ++i) Vsm[(vdg * 16 + i) * 40 + vs] = tmp[i];
    }
    __syncthreads();
    if (st * 32 <= my_q_hi) {
      f32x4 sacc[2] = {};
#pragma unroll
      for (int sb = 0; sb < 2; ++sb)
#pragma unroll
        for (int ds = 0; ds < 4; ++ds) {
          short8 kf = *reinterpret_cast<const short8*>(&Ksm[(sb * 16 + r) * 136 + ds * 32 + G * 8]);
          sacc[sb] = mfma16x16x32(kf, qf[ds], sacc[sb]);
        }
      float vals[8];
      float mymax = NEG_INF;
#pragma unroll
      for (int sb = 0; sb < 2; ++sb)
#pragma unroll
        for (int j = 0; j < 4; ++j) {
          int sIdx = st * 32 + sb * 16 + G * 4 + j;
          float v = sacc[sb][j] * SCALE_;
          v = (sIdx <= my_q) ? v : NEG_INF;
          vals[sb * 4 + j] = v;
          mymax = fmaxf(mymax, v);
        }
      mymax = fmaxf(mymax, __shfl_xor(mymax, 16));
      mymax = fmaxf(mymax, __shfl_xor(mymax, 32));
      float m_new = fmaxf(m_run, mymax);
      float factor = __expf(m_run - m_new);
      float psum = 0.f;
      float pv_[8];
#pragma unroll
      for (int i = 0; i < 8; ++i) {
        float p = __expf(vals[i] - m_new);
        psum += p;
        pv_[i] = p;
      }
      psum += __shfl_xor(psum, 16);
      psum += __shfl_xor(psum, 32);
      l_run = l_run * factor + psum;
      m_run = m_new;
#pragma unroll
      for (int i = 0; i < 8; ++i)
        Psm[wave][r][(i >> 2) * 16 + G * 4 + (i & 3)] = f2bf(pv_[i]);
      asm volatile("s_waitcnt lgkmcnt(0)" ::: "memory");
      __builtin_amdgcn_sched_barrier(0);
      short8 pf = *reinterpret_cast<const short8*>(&Psm[wave][r][G * 8]);
      float frow[4];
#pragma unroll
      for (int rr = 0; rr < 4; ++rr) frow[rr] = __shfl(factor, G * 4 + rr);
#pragma unroll
      for (int dt = 0; dt < 8; ++dt)
#pragma unroll
        for (int rr = 0; rr < 4; ++rr) acc[dt][rr] *= frow[rr];
#pragma unroll
      for (int dt = 0; dt < 8; ++dt) {
        short8 vf = *reinterpret_cast<const short8*>(&Vsm[(dt * 16 + r) * 40 + G * 8]);
        acc[dt] = mfma16x16x32(pf, vf, acc[dt]);
      }
    }
  }
  float inv = 1.0f / l_run;
  float irow[4];
#pragma unroll
  for (int rr = 0; rr < 4; ++rr) irow[rr] = __shfl(inv, G * 4 + rr);
#pragma unroll
  for (int dt = 0; dt < 8; ++dt)
#pragma unroll
    for (int rr = 0; rr < 4; ++rr) {
      size_t rowi = (size_t)(b * Q_ + q0w + G * 4 + rr) * HID_;
      attn[rowi + h * D_ + dt * 16 + r] = f2bf(acc[dt][rr] * irow[rr]);
    }
}

// ---------------- launch ----------------
extern "C" void kernel_launch(void* const* d_in, const int* in_sizes, int n_in,
                              void* d_out, int out_size, void* d_ws, size_t ws_size,
                              hipStream_t stream) {
  const float* hidden = (const float*)d_in[0];
  const float* w_qkv  = (const float*)d_in[1];
  const float* w_o    = (const float*)d_in[2];
  float* out = (float*)d_out;
  char* ws = (char*)d_ws;
  char* od = (char*)d_out;
  // scratch layout (ws 64 MiB + d_out 64 MiB):
  //   d_out[ 0:32M) hid_bf (bf16 4096x4096)      -> dead after GEMM1
  //   d_out[32M:64M) q_bf  (bf16 4096x4096, unroped) -> dead after attn
  //   ws   [ 0:48M) wqkvT  (bf16 6144x4096)      -> dead after GEMM1
  //   ws   [48M:64M) kv_ws (bf16 4096x2048)      -> k roped in place; dead after attn
  //   ws   [ 0:32M) attn_bf (after GEMM1)
  //   ws   [32M:64M) woT   (bf16 4096x4096, after attn)
  short* hid_bf  = (short*)(od + 0);
  short* q_bf    = (short*)(od + 33554432);
  short* wqkvT   = (short*)(ws + 0);
  short* kv_ws   = (short*)(ws + 50331648);
  short* attn_bf = (short*)(ws + 0);
  short* woT     = (short*)(ws + 33554432);

  k_cvt<<<dim3(16384), dim3(256), 0, stream>>>(hidden, hid_bf, HID_ * B_ * Q_);
  k_cvt_t<<<dim3(192, 128), dim3(256), 0, stream>>>(w_qkv, wqkvT, HID_, NQKV_);
  // GEMM1: one dispatch, N=6144 (48x32 = 1536 wgs, 6/CU)
  k_gemm1<<<dim3(48, 32), dim3(256), 0, stream>>>(hid_bf, wqkvT, q_bf, kv_ws);
  // RoPE in place: k only (q-rope fused into k_attn's Q load)
  k_rope_bf<<<dim3(B_ * Q_), dim3(256), 0, stream>>>(kv_ws, HKV_, 2048);
  // attention -> attn_bf (ws+0, wqkvT dead)
  k_attn<<<dim3(16, 32, 4), dim3(256), 0, stream>>>(q_bf, kv_ws, attn_bf);
  // w_o^T into ws[32M:64M) (wqkvT tail + kv dead after attn), then GEMM2 -> d_out f32
  k_cvt_t<<<dim3(128, 128), dim3(256), 0, stream>>>(w_o, woT, HID_, HID_);
  k_gemm2<<<dim3(32, 32), dim3(256), 0, stream>>>(attn_bf, woT, out);
}